// Round 12
// baseline (250.063 us; speedup 1.0000x reference)
//
#include <hip/hip_runtime.h>

#define IN_F  32
#define HID_F 64
#define OUT_F 32

#define BKT_SHIFT 8            // 256 nodes per bucket
#define BKT_NODES 256
#define NBLK      512          // partition blocks — count/append edge->block map MUST match
#define PLACE_CAP 5632         // LDS ints for bucket window (22 KB); mean 4092, 5 sigma ~4400

// bf16 helpers (round-to-nearest-even; inputs are finite)
__device__ inline unsigned short f2bf(float f) {
    unsigned u = __float_as_uint(f);
    return (unsigned short)((u + 0x7FFF + ((u >> 16) & 1)) >> 16);
}
// packed-pair unpack: word = (bf16 hi << 16) | bf16 lo ; lo = even feature
__device__ inline float bflo(unsigned w) { return __uint_as_float(w << 16); }
__device__ inline float bfhi(unsigned w) { return __uint_as_float(w & 0xFFFF0000u); }

// ================= phase 1: per-(bucket,block) exact counts =================
__global__ __launch_bounds__(256) void count_kernel(const int* __restrict__ dst,
                                                    int* __restrict__ cnt, int E, int nb)
{
    __shared__ int hist[1024];          // nb <= 1024
    int tid = threadIdx.x;
    for (int i = tid; i < nb; i += 256) hist[i] = 0;
    __syncthreads();
    for (int e = blockIdx.x * 256 + tid; e < E; e += NBLK * 256)
        atomicAdd(&hist[dst[e] >> BKT_SHIFT], 1);
    __syncthreads();
    for (int i = tid; i < nb; i += 256) cnt[i * NBLK + blockIdx.x] = hist[i];
}

// ================= phase 2a: per-bucket totals (one block per bucket) =================
__global__ __launch_bounds__(NBLK) void bsum_kernel(const int* __restrict__ cnt,
                                                    int* __restrict__ bsum)
{
    __shared__ int s[NBLK];
    int tid = threadIdx.x, b = blockIdx.x;
    s[tid] = cnt[b * NBLK + tid];
    __syncthreads();
    for (int off = NBLK / 2; off > 0; off >>= 1) {
        if (tid < off) s[tid] += s[tid + off];
        __syncthreads();
    }
    if (tid == 0) bsum[b] = s[0];
}

// ================= phase 2b: one-block exclusive scan of bucket totals =================
__global__ __launch_bounds__(512) void bscan_kernel(int* __restrict__ bsum, int nb,
                                                    int* __restrict__ cellstart, int nc,
                                                    int* __restrict__ rowstart, int n, int E)
{
    __shared__ int s[512];
    int tid = threadIdx.x;
    int my = (tid < nb) ? bsum[tid] : 0;
    s[tid] = my;
    __syncthreads();
    for (int off = 1; off < 512; off <<= 1) {
        int t = (tid >= off) ? s[tid - off] : 0;
        __syncthreads();
        s[tid] += t;
        __syncthreads();
    }
    if (tid < nb) bsum[tid] = s[tid] - my;      // exclusive bucket start
    if (tid == 0) { cellstart[nc] = E; rowstart[n] = E; }
}

// ================= phase 2c: per-bucket scan of its NBLK cells =================
__global__ __launch_bounds__(NBLK) void cscan_kernel(const int* __restrict__ cnt,
                                                     const int* __restrict__ bsum,
                                                     int* __restrict__ cellstart)
{
    __shared__ int s[NBLK];
    int tid = threadIdx.x, b = blockIdx.x;
    int my = cnt[b * NBLK + tid];
    s[tid] = my;
    __syncthreads();
    for (int off = 1; off < NBLK; off <<= 1) {
        int t = (tid >= off) ? s[tid - off] : 0;
        __syncthreads();
        s[tid] += t;
        __syncthreads();
    }
    cellstart[b * NBLK + tid] = bsum[b] + s[tid] - my;   // exclusive
}

// ================= phase 3: append via block-private LDS cursors =================
__global__ __launch_bounds__(256) void append_kernel(
    const int* __restrict__ src, const int* __restrict__ dst,
    const int* __restrict__ cellstart, unsigned* __restrict__ pairs, int E, int nb)
{
    __shared__ int cur[1024];
    int tid = threadIdx.x;
    for (int i = tid; i < nb; i += 256) cur[i] = cellstart[i * NBLK + blockIdx.x];
    __syncthreads();
    for (int e = blockIdx.x * 256 + tid; e < E; e += NBLK * 256) {
        int d = dst[e];
        int pos = atomicAdd(&cur[d >> BKT_SHIFT], 1);     // LDS atomic
        pairs[pos] = ((unsigned)src[e] << BKT_SHIFT) | (unsigned)(d & (BKT_NODES - 1));
    }
}

// ================= phase 4: per-bucket place + per-row SORT + rowstart + dinv =====
// Scatter the bucket's srcs into LDS, insertion-sort each row ascending (turns the
// downstream gathers into a coordinated low->high sweep of the feature table ->
// L2-resident window), then write out coalesced.
__global__ __launch_bounds__(256) void place_kernel(
    const int* __restrict__ cellstart, const unsigned* __restrict__ pairs,
    int* __restrict__ srcs, int* __restrict__ rowstart, float* __restrict__ dinv, int n)
{
    __shared__ int hist[BKT_NODES];
    __shared__ int ofs[BKT_NODES];
    __shared__ int buf[PLACE_CAP];      // 22 KB
    int b = blockIdx.x, tid = threadIdx.x;
    int beg = cellstart[b * NBLK], end = cellstart[(b + 1) * NBLK];
    int len = end - beg;
    hist[tid] = 0;
    __syncthreads();
    for (int e = beg + tid; e < end; e += 256)
        atomicAdd(&hist[pairs[e] & (BKT_NODES - 1)], 1);
    __syncthreads();
    int my = hist[tid];
    ofs[tid] = my;
    __syncthreads();
    for (int off = 1; off < 256; off <<= 1) {
        int t = (tid >= off) ? ofs[tid - off] : 0;
        __syncthreads();
        ofs[tid] += t;
        __syncthreads();
    }
    int excl = ofs[tid] - my;           // exclusive local offset of row `tid`
    int node = b * BKT_NODES + tid;
    if (node < n) {
        rowstart[node] = beg + excl;
        dinv[node] = rsqrtf((float)(my + 1));   // +1 self-loop
    }
    __syncthreads();
    ofs[tid] = excl;                    // reuse as LDS cursor
    __syncthreads();
    if (len <= PLACE_CAP) {
        // scatter into LDS
        for (int e = beg + tid; e < end; e += 256) {
            unsigned p = pairs[e];
            int dl = p & (BKT_NODES - 1);
            int pos = atomicAdd(&ofs[dl], 1);
            buf[pos] = (int)(p >> BKT_SHIFT);
        }
        __syncthreads();
        // per-row insertion sort (thread tid owns row tid: [excl, excl+my))
        for (int i = excl + 1; i < excl + my; ++i) {
            int v = buf[i];
            int k = i - 1;
            while (k >= excl && buf[k] > v) { buf[k + 1] = buf[k]; --k; }
            buf[k + 1] = v;
        }
        __syncthreads();
        // coalesced write-out
        for (int e = tid; e < len; e += 256)
            srcs[beg + e] = buf[e];
    } else {
        // fallback (oversized bucket): unsorted global scatter — still correct
        for (int e = beg + tid; e < end; e += 256) {
            unsigned p = pairs[e];
            int dl = p & (BKT_NODES - 1);
            int pos = beg + atomicAdd(&ofs[dl], 1);
            srcs[pos] = (int)(p >> BKT_SHIFT);
        }
    }
}

// ================= xs[i][j] = bf16(dinv[i] * x[i][j]) =================
__global__ void xs_kernel(const float* __restrict__ x, const float* __restrict__ dinv,
                          unsigned short* __restrict__ xsb, int n) {
    int t = blockIdx.x * blockDim.x + threadIdx.x;
    if (t < n * (IN_F / 4)) {
        float d = dinv[t >> 3];
        float4 v = ((const float4*)x)[t];
        ushort4 o;
        o.x = f2bf(v.x * d); o.y = f2bf(v.y * d);
        o.z = f2bf(v.z * d); o.w = f2bf(v.w * d);
        ((ushort4*)xsb)[t] = o;
    }
}

// ================= fused1: quarter-wave gather -> MLP -> packed bf16 hs2 =================
// 16 nodes/block, 16 lanes per node, lane q handles packed features (2q, 2q+1).
__global__ __launch_bounds__(256) void fused1_kernel(
    const int* __restrict__ rowstart, const int* __restrict__ srcs,
    const unsigned* __restrict__ xs2, const float* __restrict__ dinv,
    const float* __restrict__ b1, const float* __restrict__ W1,
    const float* __restrict__ W2, unsigned* __restrict__ hs2p, int n)
{
    __shared__ float W1s[IN_F * HID_F];    // 8 KB  [k*64+j]
    __shared__ float W2s[HID_F * OUT_F];   // 8 KB  [k*32+j]
    __shared__ float grow[16][IN_F + 1];   // padded: bank = (nl+k)%32
    __shared__ float hrow[16][HID_F + 1];  // padded
    int tid = threadIdx.x;
    for (int t = tid; t < IN_F * HID_F; t += 256) W1s[t] = W1[t];
    for (int t = tid; t < HID_F * OUT_F; t += 256) W2s[t] = W2[t];

    int nl = tid >> 4;                 // node-local 0..15
    unsigned q = tid & 15;             // feature-pair index
    int node = blockIdx.x * 16 + nl;
    bool active = node < n;
    int nodec = active ? node : 0;

    int beg = rowstart[nodec], end = active ? rowstart[nodec + 1] : beg;
    unsigned ws = active ? xs2[((unsigned)nodec << 4) + q] : 0u;   // self-loop
    float a0l = bflo(ws), a0h = bfhi(ws);
    float a1l = 0.f, a1h = 0.f, a2l = 0.f, a2h = 0.f, a3l = 0.f, a3h = 0.f;
    float a4l = 0.f, a4h = 0.f, a5l = 0.f, a5h = 0.f, a6l = 0.f, a6h = 0.f;
    float a7l = 0.f, a7h = 0.f;
    int e = beg;
    for (; e + 8 <= end; e += 8) {
        unsigned o0 = ((unsigned)srcs[e]     << 4) + q, o1 = ((unsigned)srcs[e + 1] << 4) + q;
        unsigned o2 = ((unsigned)srcs[e + 2] << 4) + q, o3 = ((unsigned)srcs[e + 3] << 4) + q;
        unsigned o4 = ((unsigned)srcs[e + 4] << 4) + q, o5 = ((unsigned)srcs[e + 5] << 4) + q;
        unsigned o6 = ((unsigned)srcs[e + 6] << 4) + q, o7 = ((unsigned)srcs[e + 7] << 4) + q;
        unsigned w0 = xs2[o0], w1 = xs2[o1], w2 = xs2[o2], w3 = xs2[o3];
        unsigned w4 = xs2[o4], w5 = xs2[o5], w6 = xs2[o6], w7 = xs2[o7];
        a0l += bflo(w0); a0h += bfhi(w0); a1l += bflo(w1); a1h += bfhi(w1);
        a2l += bflo(w2); a2h += bfhi(w2); a3l += bflo(w3); a3h += bfhi(w3);
        a4l += bflo(w4); a4h += bfhi(w4); a5l += bflo(w5); a5h += bfhi(w5);
        a6l += bflo(w6); a6h += bfhi(w6); a7l += bflo(w7); a7h += bfhi(w7);
    }
    for (; e + 4 <= end; e += 4) {
        unsigned o0 = ((unsigned)srcs[e]     << 4) + q, o1 = ((unsigned)srcs[e + 1] << 4) + q;
        unsigned o2 = ((unsigned)srcs[e + 2] << 4) + q, o3 = ((unsigned)srcs[e + 3] << 4) + q;
        unsigned w0 = xs2[o0], w1 = xs2[o1], w2 = xs2[o2], w3 = xs2[o3];
        a0l += bflo(w0); a0h += bfhi(w0); a1l += bflo(w1); a1h += bfhi(w1);
        a2l += bflo(w2); a2h += bfhi(w2); a3l += bflo(w3); a3h += bfhi(w3);
    }
    for (; e < end; ++e) {
        unsigned w0 = xs2[((unsigned)srcs[e] << 4) + q];
        a0l += bflo(w0); a0h += bfhi(w0);
    }
    float dv = dinv[nodec];
    grow[nl][2 * q]     = dv * (((a0l + a1l) + (a2l + a3l)) + ((a4l + a5l) + (a6l + a7l)));
    grow[nl][2 * q + 1] = dv * (((a0h + a1h) + (a2h + a3h)) + ((a4h + a5h) + (a6h + a7h)));
    __syncthreads();

    // ---- MLP: 16 threads/node. hidden features q, q+16, q+32, q+48 ----
    float h0 = b1[q], h1 = b1[q + 16], h2 = b1[q + 32], h3 = b1[q + 48];
    #pragma unroll
    for (int k = 0; k < IN_F; ++k) {
        float gk = grow[nl][k];
        h0 += gk * W1s[k * HID_F + q];
        h1 += gk * W1s[k * HID_F + q + 16];
        h2 += gk * W1s[k * HID_F + q + 32];
        h3 += gk * W1s[k * HID_F + q + 48];
    }
    hrow[nl][q]      = fmaxf(h0, 0.f);
    hrow[nl][q + 16] = fmaxf(h1, 0.f);
    hrow[nl][q + 32] = fmaxf(h2, 0.f);
    hrow[nl][q + 48] = fmaxf(h3, 0.f);
    __syncthreads();

    // ---- W2 matvec: output features 2q, 2q+1; write packed pair ----
    float p0 = 0.f, p1 = 0.f;
    #pragma unroll
    for (int k = 0; k < HID_F; ++k) {
        float hk = hrow[nl][k];
        p0 += hk * W2s[k * OUT_F + 2 * q];
        p1 += hk * W2s[k * OUT_F + 2 * q + 1];
    }
    if (active) {
        unsigned pack = (unsigned)f2bf(dv * p0) | ((unsigned)f2bf(dv * p1) << 16);
        hs2p[((unsigned)node << 4) + q] = pack;
    }
}

// ================= agg2: quarter-wave gather of packed hs2, finalize =================
__global__ __launch_bounds__(256) void agg2_kernel(
    const int* __restrict__ rowstart, const int* __restrict__ srcs,
    const unsigned* __restrict__ hs2p, const float* __restrict__ dinv,
    const float* __restrict__ b2, float* __restrict__ out, int n)
{
    int t = blockIdx.x * blockDim.x + threadIdx.x;
    int node = t >> 4;
    if (node >= n) return;
    unsigned q = t & 15;
    int beg = rowstart[node], end = rowstart[node + 1];
    unsigned ws = hs2p[((unsigned)node << 4) + q];   // self-loop
    float a0l = bflo(ws), a0h = bfhi(ws);
    float a1l = 0.f, a1h = 0.f, a2l = 0.f, a2h = 0.f, a3l = 0.f, a3h = 0.f;
    float a4l = 0.f, a4h = 0.f, a5l = 0.f, a5h = 0.f, a6l = 0.f, a6h = 0.f;
    float a7l = 0.f, a7h = 0.f;
    int e = beg;
    for (; e + 8 <= end; e += 8) {
        unsigned o0 = ((unsigned)srcs[e]     << 4) + q, o1 = ((unsigned)srcs[e + 1] << 4) + q;
        unsigned o2 = ((unsigned)srcs[e + 2] << 4) + q, o3 = ((unsigned)srcs[e + 3] << 4) + q;
        unsigned o4 = ((unsigned)srcs[e + 4] << 4) + q, o5 = ((unsigned)srcs[e + 5] << 4) + q;
        unsigned o6 = ((unsigned)srcs[e + 6] << 4) + q, o7 = ((unsigned)srcs[e + 7] << 4) + q;
        unsigned w0 = hs2p[o0], w1 = hs2p[o1], w2 = hs2p[o2], w3 = hs2p[o3];
        unsigned w4 = hs2p[o4], w5 = hs2p[o5], w6 = hs2p[o6], w7 = hs2p[o7];
        a0l += bflo(w0); a0h += bfhi(w0); a1l += bflo(w1); a1h += bfhi(w1);
        a2l += bflo(w2); a2h += bfhi(w2); a3l += bflo(w3); a3h += bfhi(w3);
        a4l += bflo(w4); a4h += bfhi(w4); a5l += bflo(w5); a5h += bfhi(w5);
        a6l += bflo(w6); a6h += bfhi(w6); a7l += bflo(w7); a7h += bfhi(w7);
    }
    for (; e + 4 <= end; e += 4) {
        unsigned o0 = ((unsigned)srcs[e]     << 4) + q, o1 = ((unsigned)srcs[e + 1] << 4) + q;
        unsigned o2 = ((unsigned)srcs[e + 2] << 4) + q, o3 = ((unsigned)srcs[e + 3] << 4) + q;
        unsigned w0 = hs2p[o0], w1 = hs2p[o1], w2 = hs2p[o2], w3 = hs2p[o3];
        a0l += bflo(w0); a0h += bfhi(w0); a1l += bflo(w1); a1h += bfhi(w1);
        a2l += bflo(w2); a2h += bfhi(w2); a3l += bflo(w3); a3h += bfhi(w3);
    }
    for (; e < end; ++e) {
        unsigned w0 = hs2p[((unsigned)srcs[e] << 4) + q];
        a0l += bflo(w0); a0h += bfhi(w0);
    }
    float dvv = dinv[node];
    float2 r;
    r.x = dvv * (((a0l + a1l) + (a2l + a3l)) + ((a4l + a5l) + (a6l + a7l))) + b2[2 * q];
    r.y = dvv * (((a0h + a1h) + (a2h + a3h)) + ((a4h + a5h) + (a6h + a7h))) + b2[2 * q + 1];
    ((float2*)out)[((size_t)node << 4) + q] = r;
}

extern "C" void kernel_launch(void* const* d_in, const int* in_sizes, int n_in,
                              void* d_out, int out_size, void* d_ws, size_t ws_size,
                              hipStream_t stream) {
    const float* x  = (const float*)d_in[0];
    const int*   ei = (const int*)  d_in[1];
    const float* W1 = (const float*)d_in[2];
    const float* b1 = (const float*)d_in[3];
    const float* W2 = (const float*)d_in[4];
    const float* b2 = (const float*)d_in[5];
    float* out = (float*)d_out;

    const int n = in_sizes[0] / IN_F;     // 100000
    const int E = in_sizes[1] / 2;        // 1600000
    const int* src = ei;
    const int* dst = ei + E;

    const int nb = (n + BKT_NODES - 1) >> BKT_SHIFT;   // 391 buckets (<=512)
    const int nc = nb * NBLK;                          // 200192 cells

    // ---- workspace layout: ~27 MB ----
    int* ip = (int*)d_ws;
    int* cnt       = ip;                 ip += nc;         // 0.8 MB
    int* cellstart = ip;                 ip += nc + 1;     // 0.8 MB
    int* bsum      = ip;                 ip += nb + 1;
    int* rowstart  = ip;                 ip += n + 1;
    unsigned* pairs = (unsigned*)ip;     ip += E;          // 6.4 MB
    int* srcs_srt  = ip;                 ip += E;          // 6.4 MB
    float* dinv = (float*)ip;            ip += n;
    unsigned* xs2  = (unsigned*)ip;      ip += (size_t)n * IN_F / 2;   // 6.4 MB
    unsigned* hs2p = (unsigned*)ip;                                    // 6.4 MB

    count_kernel<<<NBLK, 256, 0, stream>>>(dst, cnt, E, nb);
    bsum_kernel <<<nb, NBLK, 0, stream>>>(cnt, bsum);
    bscan_kernel<<<1, 512, 0, stream>>>(bsum, nb, cellstart, nc, rowstart, n, E);
    cscan_kernel<<<nb, NBLK, 0, stream>>>(cnt, bsum, cellstart);
    append_kernel<<<NBLK, 256, 0, stream>>>(src, dst, cellstart, pairs, E, nb);
    place_kernel<<<nb, 256, 0, stream>>>(cellstart, pairs, srcs_srt, rowstart, dinv, n);

    xs_kernel<<<((size_t)n * 8 + 255) / 256, 256, 0, stream>>>(x, dinv, (unsigned short*)xs2, n);

    fused1_kernel<<<(n + 15) / 16, 256, 0, stream>>>(rowstart, srcs_srt, xs2, dinv, b1, W1, W2, hs2p, n);
    agg2_kernel<<<((size_t)n * 16 + 255) / 256, 256, 0, stream>>>(rowstart, srcs_srt, hs2p, dinv, b2, out, n);
}

// Round 13
// 236.980 us; speedup vs baseline: 1.0552x; 1.0552x over previous
//
#include <hip/hip_runtime.h>

#define IN_F  32
#define HID_F 64
#define OUT_F 32

#define BKT_SHIFT 8            // 256 nodes per dst-bucket
#define BKT_NODES 256
#define NBLK      512          // partition blocks — count/append edge->block map MUST match

// bf16 helpers (round-to-nearest-even; inputs are finite)
__device__ inline unsigned short f2bf(float f) {
    unsigned u = __float_as_uint(f);
    return (unsigned short)((u + 0x7FFF + ((u >> 16) & 1)) >> 16);
}
// packed-pair unpack: word = (bf16 hi << 16) | bf16 lo ; lo = even feature
__device__ inline float bflo(unsigned w) { return __uint_as_float(w << 16); }
__device__ inline float bfhi(unsigned w) { return __uint_as_float(w & 0xFFFF0000u); }

// ================= phase 1: per-(cell,block) counts; cell = srcHalf*nb0 + dstBucket =====
__global__ __launch_bounds__(256) void count_kernel(const int* __restrict__ src,
                                                    const int* __restrict__ dst,
                                                    int* __restrict__ cnt, int E,
                                                    int nb0, int half_n)
{
    __shared__ int hist[1024];          // 2*nb0 <= 1024
    int tid = threadIdx.x;
    int nb = 2 * nb0;
    for (int i = tid; i < nb; i += 256) hist[i] = 0;
    __syncthreads();
    for (int e = blockIdx.x * 256 + tid; e < E; e += NBLK * 256) {
        int cell = ((src[e] >= half_n) ? nb0 : 0) + (dst[e] >> BKT_SHIFT);
        atomicAdd(&hist[cell], 1);
    }
    __syncthreads();
    for (int i = tid; i < nb; i += 256) cnt[i * NBLK + blockIdx.x] = hist[i];
}

// ================= phase 2a: per-cell totals =================
__global__ __launch_bounds__(NBLK) void bsum_kernel(const int* __restrict__ cnt,
                                                    int* __restrict__ bsum)
{
    __shared__ int s[NBLK];
    int tid = threadIdx.x, b = blockIdx.x;
    s[tid] = cnt[b * NBLK + tid];
    __syncthreads();
    for (int off = NBLK / 2; off > 0; off >>= 1) {
        if (tid < off) s[tid] += s[tid + off];
        __syncthreads();
    }
    if (tid == 0) bsum[b] = s[0];
}

// ================= phase 2b: one-block exclusive scan of nb (<=1024) cell totals =====
__global__ __launch_bounds__(1024) void bscan_kernel(int* __restrict__ bsum, int nb,
                                                     int* __restrict__ cellstart, int nc, int E)
{
    __shared__ int s[1024];
    int tid = threadIdx.x;
    int my = (tid < nb) ? bsum[tid] : 0;
    s[tid] = my;
    __syncthreads();
    for (int off = 1; off < 1024; off <<= 1) {
        int t = (tid >= off) ? s[tid - off] : 0;
        __syncthreads();
        s[tid] += t;
        __syncthreads();
    }
    if (tid < nb) bsum[tid] = s[tid] - my;      // exclusive cell-group start
    if (tid == 0) cellstart[nc] = E;
}

// ================= phase 2c: per-cell-group scan of its NBLK cells =================
__global__ __launch_bounds__(NBLK) void cscan_kernel(const int* __restrict__ cnt,
                                                     const int* __restrict__ bsum,
                                                     int* __restrict__ cellstart)
{
    __shared__ int s[NBLK];
    int tid = threadIdx.x, b = blockIdx.x;
    int my = cnt[b * NBLK + tid];
    s[tid] = my;
    __syncthreads();
    for (int off = 1; off < NBLK; off <<= 1) {
        int t = (tid >= off) ? s[tid - off] : 0;
        __syncthreads();
        s[tid] += t;
        __syncthreads();
    }
    cellstart[b * NBLK + tid] = bsum[b] + s[tid] - my;   // exclusive
}

// ================= phase 3: append via block-private LDS cursors =================
__global__ __launch_bounds__(256) void append_kernel(
    const int* __restrict__ src, const int* __restrict__ dst,
    const int* __restrict__ cellstart, unsigned* __restrict__ pairs, int E,
    int nb0, int half_n)
{
    __shared__ int cur[1024];
    int tid = threadIdx.x;
    int nb = 2 * nb0;
    for (int i = tid; i < nb; i += 256) cur[i] = cellstart[i * NBLK + blockIdx.x];
    __syncthreads();
    for (int e = blockIdx.x * 256 + tid; e < E; e += NBLK * 256) {
        int s = src[e], d = dst[e];
        int cell = ((s >= half_n) ? nb0 : 0) + (d >> BKT_SHIFT);
        int pos = atomicAdd(&cur[cell], 1);     // LDS atomic
        pairs[pos] = ((unsigned)s << BKT_SHIFT) | (unsigned)(d & (BKT_NODES - 1));
    }
}

// ================= phase 4: per-(half,bucket) place; writes rowstart_lo/hi =====
__global__ __launch_bounds__(256) void place_kernel(
    const int* __restrict__ cellstart, const unsigned* __restrict__ pairs,
    int* __restrict__ srcs, int* __restrict__ rs_lo, int* __restrict__ rs_hi,
    int n, int nb0)
{
    __shared__ int hist[BKT_NODES];
    __shared__ int ofs[BKT_NODES];
    int c = blockIdx.x, tid = threadIdx.x;
    int half = (c >= nb0) ? 1 : 0;
    int b = c - half * nb0;
    int* rs = half ? rs_hi : rs_lo;
    int beg = cellstart[c * NBLK], end = cellstart[(c + 1) * NBLK];
    hist[tid] = 0;
    __syncthreads();
    for (int e = beg + tid; e < end; e += 256)
        atomicAdd(&hist[pairs[e] & (BKT_NODES - 1)], 1);
    __syncthreads();
    int my = hist[tid];
    ofs[tid] = my;
    __syncthreads();
    for (int off = 1; off < 256; off <<= 1) {
        int t = (tid >= off) ? ofs[tid - off] : 0;
        __syncthreads();
        ofs[tid] += t;
        __syncthreads();
    }
    int excl = ofs[tid] - my;
    int node = b * BKT_NODES + tid;
    if (node < n)  rs[node] = beg + excl;
    if (node == n - 1) rs[n] = beg + excl + my;   // region end sentinel (no edges target >= n)
    __syncthreads();
    ofs[tid] = excl;                    // reuse as LDS cursor
    __syncthreads();
    for (int e = beg + tid; e < end; e += 256) {
        unsigned p = pairs[e];
        int dl = p & (BKT_NODES - 1);
        int pos = beg + atomicAdd(&ofs[dl], 1);
        srcs[pos] = (int)(p >> BKT_SHIFT);
    }
}

// ================= dinv from the two rowstart arrays (deg = lo len + hi len) =====
__global__ void dinv_kernel(const int* __restrict__ rs_lo, const int* __restrict__ rs_hi,
                            float* __restrict__ dinv, int n)
{
    int i = blockIdx.x * blockDim.x + threadIdx.x;
    if (i < n) {
        int deg = (rs_lo[i + 1] - rs_lo[i]) + (rs_hi[i + 1] - rs_hi[i]);
        dinv[i] = rsqrtf((float)(deg + 1));   // +1 self-loop
    }
}

// ================= xs[i][j] = bf16(dinv[i] * x[i][j]) =================
__global__ void xs_kernel(const float* __restrict__ x, const float* __restrict__ dinv,
                          unsigned short* __restrict__ xsb, int n) {
    int t = blockIdx.x * blockDim.x + threadIdx.x;
    if (t < n * (IN_F / 4)) {
        float d = dinv[t >> 3];
        float4 v = ((const float4*)x)[t];
        ushort4 o;
        o.x = f2bf(v.x * d); o.y = f2bf(v.y * d);
        o.z = f2bf(v.z * d); o.w = f2bf(v.w * d);
        ((ushort4*)xsb)[t] = o;
    }
}

// ================= gather-half: partial sums over one src-range segment =================
// quarter-wave per node; table slice = 3.2 MB (L2-resident within this launch).
// Used for layer1-lo (tab=xs2) and layer2-lo (tab=hs2p). No barriers -> early return ok.
__global__ __launch_bounds__(256) void gather_half_kernel(
    const int* __restrict__ rs, const int* __restrict__ srcs,
    const unsigned* __restrict__ tab, float2* __restrict__ acc, int n)
{
    int tid = threadIdx.x;
    int nl = tid >> 4;
    unsigned q = tid & 15;
    int node = blockIdx.x * 16 + nl;
    if (node >= n) return;
    int beg = rs[node], end = rs[node + 1];
    float a0l = 0.f, a0h = 0.f, a1l = 0.f, a1h = 0.f, a2l = 0.f, a2h = 0.f;
    float a3l = 0.f, a3h = 0.f, a4l = 0.f, a4h = 0.f, a5l = 0.f, a5h = 0.f;
    float a6l = 0.f, a6h = 0.f, a7l = 0.f, a7h = 0.f;
    int e = beg;
    for (; e + 8 <= end; e += 8) {
        unsigned o0 = ((unsigned)srcs[e]     << 4) + q, o1 = ((unsigned)srcs[e + 1] << 4) + q;
        unsigned o2 = ((unsigned)srcs[e + 2] << 4) + q, o3 = ((unsigned)srcs[e + 3] << 4) + q;
        unsigned o4 = ((unsigned)srcs[e + 4] << 4) + q, o5 = ((unsigned)srcs[e + 5] << 4) + q;
        unsigned o6 = ((unsigned)srcs[e + 6] << 4) + q, o7 = ((unsigned)srcs[e + 7] << 4) + q;
        unsigned w0 = tab[o0], w1 = tab[o1], w2 = tab[o2], w3 = tab[o3];
        unsigned w4 = tab[o4], w5 = tab[o5], w6 = tab[o6], w7 = tab[o7];
        a0l += bflo(w0); a0h += bfhi(w0); a1l += bflo(w1); a1h += bfhi(w1);
        a2l += bflo(w2); a2h += bfhi(w2); a3l += bflo(w3); a3h += bfhi(w3);
        a4l += bflo(w4); a4h += bfhi(w4); a5l += bflo(w5); a5h += bfhi(w5);
        a6l += bflo(w6); a6h += bfhi(w6); a7l += bflo(w7); a7h += bfhi(w7);
    }
    for (; e + 4 <= end; e += 4) {
        unsigned o0 = ((unsigned)srcs[e]     << 4) + q, o1 = ((unsigned)srcs[e + 1] << 4) + q;
        unsigned o2 = ((unsigned)srcs[e + 2] << 4) + q, o3 = ((unsigned)srcs[e + 3] << 4) + q;
        unsigned w0 = tab[o0], w1 = tab[o1], w2 = tab[o2], w3 = tab[o3];
        a0l += bflo(w0); a0h += bfhi(w0); a1l += bflo(w1); a1h += bfhi(w1);
        a2l += bflo(w2); a2h += bfhi(w2); a3l += bflo(w3); a3h += bfhi(w3);
    }
    for (; e < end; ++e) {
        unsigned w0 = tab[((unsigned)srcs[e] << 4) + q];
        a0l += bflo(w0); a0h += bfhi(w0);
    }
    float2 r;
    r.x = ((a0l + a1l) + (a2l + a3l)) + ((a4l + a5l) + (a6l + a7l));
    r.y = ((a0h + a1h) + (a2h + a3h)) + ((a4h + a5h) + (a6h + a7h));
    acc[((unsigned)node << 4) + q] = r;
}

// ================= fused1b: hi-half gather + partials + self + MLP -> packed hs2 =====
__global__ __launch_bounds__(256) void fused1b_kernel(
    const int* __restrict__ rs_hi, const int* __restrict__ srcs,
    const unsigned* __restrict__ xs2, const float2* __restrict__ acc,
    const float* __restrict__ dinv, const float* __restrict__ b1,
    const float* __restrict__ W1, const float* __restrict__ W2,
    unsigned* __restrict__ hs2p, int n)
{
    __shared__ float W1s[IN_F * HID_F];    // 8 KB  [k*64+j]
    __shared__ float W2s[HID_F * OUT_F];   // 8 KB  [k*32+j]
    __shared__ float grow[16][IN_F + 1];   // padded
    __shared__ float hrow[16][HID_F + 1];  // padded
    int tid = threadIdx.x;
    for (int t = tid; t < IN_F * HID_F; t += 256) W1s[t] = W1[t];
    for (int t = tid; t < HID_F * OUT_F; t += 256) W2s[t] = W2[t];

    int nl = tid >> 4;
    unsigned q = tid & 15;
    int node = blockIdx.x * 16 + nl;
    bool active = node < n;
    int nodec = active ? node : 0;

    int beg = rs_hi[nodec], end = active ? rs_hi[nodec + 1] : beg;
    float a0l = 0.f, a0h = 0.f, a1l = 0.f, a1h = 0.f, a2l = 0.f, a2h = 0.f;
    float a3l = 0.f, a3h = 0.f, a4l = 0.f, a4h = 0.f, a5l = 0.f, a5h = 0.f;
    float a6l = 0.f, a6h = 0.f, a7l = 0.f, a7h = 0.f;
    int e = beg;
    for (; e + 8 <= end; e += 8) {
        unsigned o0 = ((unsigned)srcs[e]     << 4) + q, o1 = ((unsigned)srcs[e + 1] << 4) + q;
        unsigned o2 = ((unsigned)srcs[e + 2] << 4) + q, o3 = ((unsigned)srcs[e + 3] << 4) + q;
        unsigned o4 = ((unsigned)srcs[e + 4] << 4) + q, o5 = ((unsigned)srcs[e + 5] << 4) + q;
        unsigned o6 = ((unsigned)srcs[e + 6] << 4) + q, o7 = ((unsigned)srcs[e + 7] << 4) + q;
        unsigned w0 = xs2[o0], w1 = xs2[o1], w2 = xs2[o2], w3 = xs2[o3];
        unsigned w4 = xs2[o4], w5 = xs2[o5], w6 = xs2[o6], w7 = xs2[o7];
        a0l += bflo(w0); a0h += bfhi(w0); a1l += bflo(w1); a1h += bfhi(w1);
        a2l += bflo(w2); a2h += bfhi(w2); a3l += bflo(w3); a3h += bfhi(w3);
        a4l += bflo(w4); a4h += bfhi(w4); a5l += bflo(w5); a5h += bfhi(w5);
        a6l += bflo(w6); a6h += bfhi(w6); a7l += bflo(w7); a7h += bfhi(w7);
    }
    for (; e + 4 <= end; e += 4) {
        unsigned o0 = ((unsigned)srcs[e]     << 4) + q, o1 = ((unsigned)srcs[e + 1] << 4) + q;
        unsigned o2 = ((unsigned)srcs[e + 2] << 4) + q, o3 = ((unsigned)srcs[e + 3] << 4) + q;
        unsigned w0 = xs2[o0], w1 = xs2[o1], w2 = xs2[o2], w3 = xs2[o3];
        a0l += bflo(w0); a0h += bfhi(w0); a1l += bflo(w1); a1h += bfhi(w1);
        a2l += bflo(w2); a2h += bfhi(w2); a3l += bflo(w3); a3h += bfhi(w3);
    }
    for (; e < end; ++e) {
        unsigned w0 = xs2[((unsigned)srcs[e] << 4) + q];
        a0l += bflo(w0); a0h += bfhi(w0);
    }
    float suml = ((a0l + a1l) + (a2l + a3l)) + ((a4l + a5l) + (a6l + a7l));
    float sumh = ((a0h + a1h) + (a2h + a3h)) + ((a4h + a5h) + (a6h + a7h));
    // lo-half partials + self-loop
    float2 a = acc[((unsigned)nodec << 4) + q];
    unsigned ws = xs2[((unsigned)nodec << 4) + q];
    suml += a.x + bflo(ws);
    sumh += a.y + bfhi(ws);
    float dv = dinv[nodec];
    grow[nl][2 * q]     = dv * suml;
    grow[nl][2 * q + 1] = dv * sumh;
    __syncthreads();

    float h0 = b1[q], h1 = b1[q + 16], h2 = b1[q + 32], h3 = b1[q + 48];
    #pragma unroll
    for (int k = 0; k < IN_F; ++k) {
        float gk = grow[nl][k];
        h0 += gk * W1s[k * HID_F + q];
        h1 += gk * W1s[k * HID_F + q + 16];
        h2 += gk * W1s[k * HID_F + q + 32];
        h3 += gk * W1s[k * HID_F + q + 48];
    }
    hrow[nl][q]      = fmaxf(h0, 0.f);
    hrow[nl][q + 16] = fmaxf(h1, 0.f);
    hrow[nl][q + 32] = fmaxf(h2, 0.f);
    hrow[nl][q + 48] = fmaxf(h3, 0.f);
    __syncthreads();

    float p0 = 0.f, p1 = 0.f;
    #pragma unroll
    for (int k = 0; k < HID_F; ++k) {
        float hk = hrow[nl][k];
        p0 += hk * W2s[k * OUT_F + 2 * q];
        p1 += hk * W2s[k * OUT_F + 2 * q + 1];
    }
    if (active) {
        unsigned pack = (unsigned)f2bf(dv * p0) | ((unsigned)f2bf(dv * p1) << 16);
        hs2p[((unsigned)node << 4) + q] = pack;
    }
}

// ================= agg2-hi: hi-half gather + partials + self + finalize -> out =====
__global__ __launch_bounds__(256) void agg2hi_kernel(
    const int* __restrict__ rs_hi, const int* __restrict__ srcs,
    const unsigned* __restrict__ hs2p, const float2* __restrict__ acc,
    const float* __restrict__ dinv, const float* __restrict__ b2,
    float* __restrict__ out, int n)
{
    int tid = threadIdx.x;
    int nl = tid >> 4;
    unsigned q = tid & 15;
    int node = blockIdx.x * 16 + nl;
    if (node >= n) return;
    int beg = rs_hi[node], end = rs_hi[node + 1];
    float a0l = 0.f, a0h = 0.f, a1l = 0.f, a1h = 0.f, a2l = 0.f, a2h = 0.f;
    float a3l = 0.f, a3h = 0.f, a4l = 0.f, a4h = 0.f, a5l = 0.f, a5h = 0.f;
    float a6l = 0.f, a6h = 0.f, a7l = 0.f, a7h = 0.f;
    int e = beg;
    for (; e + 8 <= end; e += 8) {
        unsigned o0 = ((unsigned)srcs[e]     << 4) + q, o1 = ((unsigned)srcs[e + 1] << 4) + q;
        unsigned o2 = ((unsigned)srcs[e + 2] << 4) + q, o3 = ((unsigned)srcs[e + 3] << 4) + q;
        unsigned o4 = ((unsigned)srcs[e + 4] << 4) + q, o5 = ((unsigned)srcs[e + 5] << 4) + q;
        unsigned o6 = ((unsigned)srcs[e + 6] << 4) + q, o7 = ((unsigned)srcs[e + 7] << 4) + q;
        unsigned w0 = hs2p[o0], w1 = hs2p[o1], w2 = hs2p[o2], w3 = hs2p[o3];
        unsigned w4 = hs2p[o4], w5 = hs2p[o5], w6 = hs2p[o6], w7 = hs2p[o7];
        a0l += bflo(w0); a0h += bfhi(w0); a1l += bflo(w1); a1h += bfhi(w1);
        a2l += bflo(w2); a2h += bfhi(w2); a3l += bflo(w3); a3h += bfhi(w3);
        a4l += bflo(w4); a4h += bfhi(w4); a5l += bflo(w5); a5h += bfhi(w5);
        a6l += bflo(w6); a6h += bfhi(w6); a7l += bflo(w7); a7h += bfhi(w7);
    }
    for (; e + 4 <= end; e += 4) {
        unsigned o0 = ((unsigned)srcs[e]     << 4) + q, o1 = ((unsigned)srcs[e + 1] << 4) + q;
        unsigned o2 = ((unsigned)srcs[e + 2] << 4) + q, o3 = ((unsigned)srcs[e + 3] << 4) + q;
        unsigned w0 = hs2p[o0], w1 = hs2p[o1], w2 = hs2p[o2], w3 = hs2p[o3];
        a0l += bflo(w0); a0h += bfhi(w0); a1l += bflo(w1); a1h += bfhi(w1);
        a2l += bflo(w2); a2h += bfhi(w2); a3l += bflo(w3); a3h += bfhi(w3);
    }
    for (; e < end; ++e) {
        unsigned w0 = hs2p[((unsigned)srcs[e] << 4) + q];
        a0l += bflo(w0); a0h += bfhi(w0);
    }
    float2 a = acc[((unsigned)node << 4) + q];
    unsigned ws = hs2p[((unsigned)node << 4) + q];
    float suml = ((a0l + a1l) + (a2l + a3l)) + ((a4l + a5l) + (a6l + a7l)) + a.x + bflo(ws);
    float sumh = ((a0h + a1h) + (a2h + a3h)) + ((a4h + a5h) + (a6h + a7h)) + a.y + bfhi(ws);
    float dvv = dinv[node];
    float2 r;
    r.x = dvv * suml + b2[2 * q];
    r.y = dvv * sumh + b2[2 * q + 1];
    ((float2*)out)[((size_t)node << 4) + q] = r;
}

extern "C" void kernel_launch(void* const* d_in, const int* in_sizes, int n_in,
                              void* d_out, int out_size, void* d_ws, size_t ws_size,
                              hipStream_t stream) {
    const float* x  = (const float*)d_in[0];
    const int*   ei = (const int*)  d_in[1];
    const float* W1 = (const float*)d_in[2];
    const float* b1 = (const float*)d_in[3];
    const float* W2 = (const float*)d_in[4];
    const float* b2 = (const float*)d_in[5];
    float* out = (float*)d_out;

    const int n = in_sizes[0] / IN_F;     // 100000
    const int E = in_sizes[1] / 2;        // 1600000
    const int* src = ei;
    const int* dst = ei + E;

    const int half_n = n >> 1;                          // src-range boundary (slice 3.2 MB)
    const int nb0 = (n + BKT_NODES - 1) >> BKT_SHIFT;   // 391 dst-buckets
    const int nb  = 2 * nb0;                            // 782 cells-groups (<=1024)
    const int nc  = nb * NBLK;                          // 400384 cells

    // ---- workspace layout: ~43 MB ----
    int* ip = (int*)d_ws;
    int* cnt       = ip;                 ip += nc;          // 1.6 MB
    int* cellstart = ip;                 ip += nc + 1;      // 1.6 MB
    int* bsum      = ip;                 ip += nb + 1;
    int* rs_lo     = ip;                 ip += n + 1;
    int* rs_hi     = ip;                 ip += n + 1;
    unsigned* pairs = (unsigned*)ip;     ip += E;           // 6.4 MB
    int* srcs_srt  = ip;                 ip += E;           // 6.4 MB
    float* dinv = (float*)ip;            ip += n;
    unsigned* xs2  = (unsigned*)ip;      ip += (size_t)n * IN_F / 2;   // 6.4 MB
    unsigned* hs2p = (unsigned*)ip;      ip += (size_t)n * IN_F / 2;   // 6.4 MB
    float2* acc    = (float2*)ip;                                      // 12.8 MB

    count_kernel<<<NBLK, 256, 0, stream>>>(src, dst, cnt, E, nb0, half_n);
    bsum_kernel <<<nb, NBLK, 0, stream>>>(cnt, bsum);
    bscan_kernel<<<1, 1024, 0, stream>>>(bsum, nb, cellstart, nc, E);
    cscan_kernel<<<nb, NBLK, 0, stream>>>(cnt, bsum, cellstart);
    append_kernel<<<NBLK, 256, 0, stream>>>(src, dst, cellstart, pairs, E, nb0, half_n);
    place_kernel<<<nb, 256, 0, stream>>>(cellstart, pairs, srcs_srt, rs_lo, rs_hi, n, nb0);
    dinv_kernel<<<(n + 255) / 256, 256, 0, stream>>>(rs_lo, rs_hi, dinv, n);
    xs_kernel<<<((size_t)n * 8 + 255) / 256, 256, 0, stream>>>(x, dinv, (unsigned short*)xs2, n);

    const int ngrid = (n + 15) / 16;
    // layer 1: lo-slice gather (table slice L2-resident), then hi + MLP
    gather_half_kernel<<<ngrid, 256, 0, stream>>>(rs_lo, srcs_srt, xs2, acc, n);
    fused1b_kernel<<<ngrid, 256, 0, stream>>>(rs_hi, srcs_srt, xs2, acc, dinv, b1, W1, W2, hs2p, n);
    // layer 2: same split on hs2p
    gather_half_kernel<<<ngrid, 256, 0, stream>>>(rs_lo, srcs_srt, hs2p, acc, n);
    agg2hi_kernel<<<ngrid, 256, 0, stream>>>(rs_hi, srcs_srt, hs2p, acc, dinv, b2, out, n);
}

// Round 14
// 229.672 us; speedup vs baseline: 1.0888x; 1.0318x over previous
//
#include <hip/hip_runtime.h>

#define IN_F  32
#define HID_F 64
#define OUT_F 32

#define BKT_SHIFT 8            // 256 nodes per bucket
#define BKT_NODES 256
#define NBLK      512          // partition blocks — count/append edge->block map MUST match

// bf16 helpers (round-to-nearest-even; inputs are finite)
__device__ inline unsigned short f2bf(float f) {
    unsigned u = __float_as_uint(f);
    return (unsigned short)((u + 0x7FFF + ((u >> 16) & 1)) >> 16);
}
// packed-pair unpack: word = (bf16 hi << 16) | bf16 lo ; lo = even feature
__device__ inline float bflo(unsigned w) { return __uint_as_float(w << 16); }
__device__ inline float bfhi(unsigned w) { return __uint_as_float(w & 0xFFFF0000u); }

// ================= phase 1: per-(bucket,block) exact counts =================
__global__ __launch_bounds__(256) void count_kernel(const int* __restrict__ dst,
                                                    int* __restrict__ cnt, int E, int nb)
{
    __shared__ int hist[1024];          // nb <= 1024
    int tid = threadIdx.x;
    for (int i = tid; i < nb; i += 256) hist[i] = 0;
    __syncthreads();
    for (int e = blockIdx.x * 256 + tid; e < E; e += NBLK * 256)
        atomicAdd(&hist[dst[e] >> BKT_SHIFT], 1);
    __syncthreads();
    for (int i = tid; i < nb; i += 256) cnt[i * NBLK + blockIdx.x] = hist[i];
}

// ================= phase 2a: per-bucket totals =================
__global__ __launch_bounds__(NBLK) void bsum_kernel(const int* __restrict__ cnt,
                                                    int* __restrict__ bsum)
{
    __shared__ int s[NBLK];
    int tid = threadIdx.x, b = blockIdx.x;
    s[tid] = cnt[b * NBLK + tid];
    __syncthreads();
    for (int off = NBLK / 2; off > 0; off >>= 1) {
        if (tid < off) s[tid] += s[tid + off];
        __syncthreads();
    }
    if (tid == 0) bsum[b] = s[0];
}

// ================= phase 2b: one-block exclusive scan of bucket totals =================
__global__ __launch_bounds__(512) void bscan_kernel(int* __restrict__ bsum, int nb,
                                                    int* __restrict__ cellstart, int nc,
                                                    int* __restrict__ rowstart, int n, int E)
{
    __shared__ int s[512];
    int tid = threadIdx.x;
    int my = (tid < nb) ? bsum[tid] : 0;
    s[tid] = my;
    __syncthreads();
    for (int off = 1; off < 512; off <<= 1) {
        int t = (tid >= off) ? s[tid - off] : 0;
        __syncthreads();
        s[tid] += t;
        __syncthreads();
    }
    if (tid < nb) bsum[tid] = s[tid] - my;      // exclusive bucket start
    if (tid == 0) { cellstart[nc] = E; rowstart[n] = E; }
}

// ================= phase 2c: per-bucket scan of its NBLK cells =================
__global__ __launch_bounds__(NBLK) void cscan_kernel(const int* __restrict__ cnt,
                                                     const int* __restrict__ bsum,
                                                     int* __restrict__ cellstart)
{
    __shared__ int s[NBLK];
    int tid = threadIdx.x, b = blockIdx.x;
    int my = cnt[b * NBLK + tid];
    s[tid] = my;
    __syncthreads();
    for (int off = 1; off < NBLK; off <<= 1) {
        int t = (tid >= off) ? s[tid - off] : 0;
        __syncthreads();
        s[tid] += t;
        __syncthreads();
    }
    cellstart[b * NBLK + tid] = bsum[b] + s[tid] - my;   // exclusive
}

// ================= phase 3: append via block-private LDS cursors =================
__global__ __launch_bounds__(256) void append_kernel(
    const int* __restrict__ src, const int* __restrict__ dst,
    const int* __restrict__ cellstart, unsigned* __restrict__ pairs, int E, int nb)
{
    __shared__ int cur[1024];
    int tid = threadIdx.x;
    for (int i = tid; i < nb; i += 256) cur[i] = cellstart[i * NBLK + blockIdx.x];
    __syncthreads();
    for (int e = blockIdx.x * 256 + tid; e < E; e += NBLK * 256) {
        int d = dst[e];
        int pos = atomicAdd(&cur[d >> BKT_SHIFT], 1);     // LDS atomic
        pairs[pos] = ((unsigned)src[e] << BKT_SHIFT) | (unsigned)(d & (BKT_NODES - 1));
    }
}

// ================= phase 4: place + rowstart + dinv + fused xs build =================
__global__ __launch_bounds__(256) void place_kernel(
    const int* __restrict__ cellstart, const unsigned* __restrict__ pairs,
    const float* __restrict__ x,
    int* __restrict__ srcs, int* __restrict__ rowstart, float* __restrict__ dinv,
    unsigned* __restrict__ xs2, int n)
{
    __shared__ int hist[BKT_NODES];
    __shared__ int ofs[BKT_NODES];
    __shared__ float sdinv[BKT_NODES];
    int b = blockIdx.x, tid = threadIdx.x;
    int beg = cellstart[b * NBLK], end = cellstart[(b + 1) * NBLK];
    hist[tid] = 0;
    __syncthreads();
    for (int e = beg + tid; e < end; e += 256)
        atomicAdd(&hist[pairs[e] & (BKT_NODES - 1)], 1);
    __syncthreads();
    int my = hist[tid];
    ofs[tid] = my;
    __syncthreads();
    for (int off = 1; off < 256; off <<= 1) {
        int t = (tid >= off) ? ofs[tid - off] : 0;
        __syncthreads();
        ofs[tid] += t;
        __syncthreads();
    }
    int excl = ofs[tid] - my;
    int node = b * BKT_NODES + tid;
    float dv = rsqrtf((float)(my + 1));   // +1 self-loop
    sdinv[tid] = dv;
    if (node < n) {
        rowstart[node] = beg + excl;
        dinv[node] = dv;
    }
    __syncthreads();
    ofs[tid] = excl;                    // reuse as LDS cursor
    __syncthreads();
    for (int e = beg + tid; e < end; e += 256) {
        unsigned p = pairs[e];
        int dl = p & (BKT_NODES - 1);
        int pos = beg + atomicAdd(&ofs[dl], 1);
        srcs[pos] = (int)(p >> BKT_SHIFT);
    }
    // fused xs: xs2[node][j] = bf16(dinv[node] * x[node][j]) for this bucket's nodes
    const float4* x4 = (const float4*)x;
    uint2* xo = (uint2*)xs2;
    for (int idx = tid; idx < BKT_NODES * 8; idx += 256) {
        int nloc = idx >> 3, g = idx & 7;
        int nd = b * BKT_NODES + nloc;
        if (nd < n) {
            float d = sdinv[nloc];
            float4 v = x4[((size_t)nd << 3) + g];
            unsigned lo = (unsigned)f2bf(v.x * d) | ((unsigned)f2bf(v.y * d) << 16);
            unsigned hi = (unsigned)f2bf(v.z * d) | ((unsigned)f2bf(v.w * d) << 16);
            xo[((size_t)nd << 3) + g] = make_uint2(lo, hi);
        }
    }
}

// ================= fused1: dwordx2 gather (8 lanes/edge) -> packed-weight MLP =====
// 16 nodes/block, 16 lanes/node. Lane p: r=p&7 owns features 4r..4r+3 (one uint2),
// hp=p>>3 selects which edge of a pair. One tab instr = 8 edges. grow/hrow are
// wave-private (one wave = 4 nodes) -> no barriers after weight staging.
__global__ __launch_bounds__(256) void fused1_kernel(
    const int* __restrict__ rowstart, const int* __restrict__ srcs,
    const unsigned* __restrict__ xs2, const float* __restrict__ dinv,
    const float* __restrict__ b1, const float* __restrict__ W1,
    const float* __restrict__ W2, unsigned* __restrict__ hs2p, int n)
{
    __shared__ float W1ps[16 * 132];   // [q]: 32 float4 taps, stride 132 (=4 mod 32 -> 2-way only)
    __shared__ float W2ps[16 * 132];   // [q]: 64 float2 taps
    __shared__ float grow[16 * 48];    // [nl][32], stride 48 (=16 mod 32)
    __shared__ float hrow[16 * 80];    // [nl][64], stride 80 (=16 mod 32)
    int tid = threadIdx.x;
    for (int t = tid; t < 16 * 32; t += 256) {
        int q = t >> 5, k = t & 31;
        *(float4*)&W1ps[q * 132 + k * 4] =
            make_float4(W1[k * HID_F + q],      W1[k * HID_F + q + 16],
                        W1[k * HID_F + q + 32], W1[k * HID_F + q + 48]);
    }
    const float2* W2f2 = (const float2*)W2;
    for (int t = tid; t < 16 * 64; t += 256) {
        int q = t >> 6, k = t & 63;
        *(float2*)&W2ps[q * 132 + k * 2] = W2f2[k * 16 + q];
    }
    __syncthreads();   // only barrier in the kernel

    int nl = tid >> 4;
    int p  = tid & 15;
    unsigned r = p & 7;
    int hp = p >> 3;
    int node = blockIdx.x * 16 + nl;
    bool active = node < n;
    int nodec = active ? node : 0;
    int beg = rowstart[nodec], end = active ? rowstart[nodec + 1] : beg;

    const uint2* tab = (const uint2*)xs2;
    float a00=0,a01=0,a02=0,a03=0, a10=0,a11=0,a12=0,a13=0;
    float a20=0,a21=0,a22=0,a23=0, a30=0,a31=0,a32=0,a33=0;
    int e = beg;
    for (; e + 8 <= end; e += 8) {
        int i0 = srcs[e + 0 + hp], i1 = srcs[e + 2 + hp];
        int i2 = srcs[e + 4 + hp], i3 = srcs[e + 6 + hp];
        uint2 w0 = tab[((unsigned)i0 << 3) + r];
        uint2 w1 = tab[((unsigned)i1 << 3) + r];
        uint2 w2 = tab[((unsigned)i2 << 3) + r];
        uint2 w3 = tab[((unsigned)i3 << 3) + r];
        a00 += bflo(w0.x); a01 += bfhi(w0.x); a02 += bflo(w0.y); a03 += bfhi(w0.y);
        a10 += bflo(w1.x); a11 += bfhi(w1.x); a12 += bflo(w1.y); a13 += bfhi(w1.y);
        a20 += bflo(w2.x); a21 += bfhi(w2.x); a22 += bflo(w2.y); a23 += bfhi(w2.y);
        a30 += bflo(w3.x); a31 += bfhi(w3.x); a32 += bflo(w3.y); a33 += bfhi(w3.y);
    }
    for (; e + 2 <= end; e += 2) {
        int i0 = srcs[e + hp];
        uint2 w0 = tab[((unsigned)i0 << 3) + r];
        a00 += bflo(w0.x); a01 += bfhi(w0.x); a02 += bflo(w0.y); a03 += bfhi(w0.y);
    }
    if (e < end && hp == 0) {            // odd remainder: lower half only
        int i0 = srcs[e];
        uint2 w0 = tab[((unsigned)i0 << 3) + r];
        a00 += bflo(w0.x); a01 += bfhi(w0.x); a02 += bflo(w0.y); a03 += bfhi(w0.y);
    }
    if (hp == 0) {                       // self-loop once
        uint2 w0 = tab[((unsigned)nodec << 3) + r];
        a10 += bflo(w0.x); a11 += bfhi(w0.x); a12 += bflo(w0.y); a13 += bfhi(w0.y);
    }
    float f0 = (a00 + a10) + (a20 + a30);
    float f1 = (a01 + a11) + (a21 + a31);
    float f2 = (a02 + a12) + (a22 + a32);
    float f3 = (a03 + a13) + (a23 + a33);
    f0 += __shfl_xor(f0, 8); f1 += __shfl_xor(f1, 8);
    f2 += __shfl_xor(f2, 8); f3 += __shfl_xor(f3, 8);
    float dv = dinv[nodec];
    if (hp == 0)
        *(float4*)&grow[nl * 48 + (int)r * 4] = make_float4(dv*f0, dv*f1, dv*f2, dv*f3);
    // wave-private LDS: no barrier needed (writers/readers in same wave)

    int q = p;                           // MLP feature-thread 0..15
    float h0 = b1[q], h1 = b1[q + 16], h2 = b1[q + 32], h3 = b1[q + 48];
    const float4* w1r = (const float4*)&W1ps[q * 132];
    #pragma unroll
    for (int k = 0; k < IN_F; ++k) {
        float gk = grow[nl * 48 + k];
        float4 w = w1r[k];
        h0 += gk * w.x; h1 += gk * w.y; h2 += gk * w.z; h3 += gk * w.w;
    }
    hrow[nl * 80 + q]      = fmaxf(h0, 0.f);
    hrow[nl * 80 + q + 16] = fmaxf(h1, 0.f);
    hrow[nl * 80 + q + 32] = fmaxf(h2, 0.f);
    hrow[nl * 80 + q + 48] = fmaxf(h3, 0.f);
    float p0 = 0.f, p1 = 0.f;
    const float2* w2r = (const float2*)&W2ps[q * 132];
    #pragma unroll
    for (int k = 0; k < HID_F; ++k) {
        float hk = hrow[nl * 80 + k];
        float2 w = w2r[k];
        p0 += hk * w.x; p1 += hk * w.y;
    }
    if (active) {
        unsigned pack = (unsigned)f2bf(dv * p0) | ((unsigned)f2bf(dv * p1) << 16);
        hs2p[((unsigned)node << 4) + q] = pack;
    }
}

// ================= agg2: dwordx2 gather of hs2p + finalize (float4 out) ==========
__global__ __launch_bounds__(256) void agg2_kernel(
    const int* __restrict__ rowstart, const int* __restrict__ srcs,
    const unsigned* __restrict__ hs2p, const float* __restrict__ dinv,
    const float* __restrict__ b2, float* __restrict__ out, int n)
{
    int tid = threadIdx.x;
    int nl = tid >> 4, p = tid & 15;
    unsigned r = p & 7;
    int hp = p >> 3;
    int node = blockIdx.x * 16 + nl;
    if (node >= n) return;               // no LDS/barriers -> safe
    int beg = rowstart[node], end = rowstart[node + 1];
    const uint2* tab = (const uint2*)hs2p;
    float a00=0,a01=0,a02=0,a03=0, a10=0,a11=0,a12=0,a13=0;
    float a20=0,a21=0,a22=0,a23=0, a30=0,a31=0,a32=0,a33=0;
    int e = beg;
    for (; e + 8 <= end; e += 8) {
        int i0 = srcs[e + 0 + hp], i1 = srcs[e + 2 + hp];
        int i2 = srcs[e + 4 + hp], i3 = srcs[e + 6 + hp];
        uint2 w0 = tab[((unsigned)i0 << 3) + r];
        uint2 w1 = tab[((unsigned)i1 << 3) + r];
        uint2 w2 = tab[((unsigned)i2 << 3) + r];
        uint2 w3 = tab[((unsigned)i3 << 3) + r];
        a00 += bflo(w0.x); a01 += bfhi(w0.x); a02 += bflo(w0.y); a03 += bfhi(w0.y);
        a10 += bflo(w1.x); a11 += bfhi(w1.x); a12 += bflo(w1.y); a13 += bfhi(w1.y);
        a20 += bflo(w2.x); a21 += bfhi(w2.x); a22 += bflo(w2.y); a23 += bfhi(w2.y);
        a30 += bflo(w3.x); a31 += bfhi(w3.x); a32 += bflo(w3.y); a33 += bfhi(w3.y);
    }
    for (; e + 2 <= end; e += 2) {
        int i0 = srcs[e + hp];
        uint2 w0 = tab[((unsigned)i0 << 3) + r];
        a00 += bflo(w0.x); a01 += bfhi(w0.x); a02 += bflo(w0.y); a03 += bfhi(w0.y);
    }
    if (e < end && hp == 0) {
        int i0 = srcs[e];
        uint2 w0 = tab[((unsigned)i0 << 3) + r];
        a00 += bflo(w0.x); a01 += bfhi(w0.x); a02 += bflo(w0.y); a03 += bfhi(w0.y);
    }
    if (hp == 0) {                       // self-loop once
        uint2 w0 = tab[((unsigned)node << 3) + r];
        a10 += bflo(w0.x); a11 += bfhi(w0.x); a12 += bflo(w0.y); a13 += bfhi(w0.y);
    }
    float f0 = (a00 + a10) + (a20 + a30);
    float f1 = (a01 + a11) + (a21 + a31);
    float f2 = (a02 + a12) + (a22 + a32);
    float f3 = (a03 + a13) + (a23 + a33);
    f0 += __shfl_xor(f0, 8); f1 += __shfl_xor(f1, 8);
    f2 += __shfl_xor(f2, 8); f3 += __shfl_xor(f3, 8);
    if (hp == 0) {
        float dvv = dinv[node];
        float4 bb = ((const float4*)b2)[r];
        float4 o;
        o.x = dvv * f0 + bb.x; o.y = dvv * f1 + bb.y;
        o.z = dvv * f2 + bb.z; o.w = dvv * f3 + bb.w;
        ((float4*)out)[((size_t)node << 3) + r] = o;
    }
}

extern "C" void kernel_launch(void* const* d_in, const int* in_sizes, int n_in,
                              void* d_out, int out_size, void* d_ws, size_t ws_size,
                              hipStream_t stream) {
    const float* x  = (const float*)d_in[0];
    const int*   ei = (const int*)  d_in[1];
    const float* W1 = (const float*)d_in[2];
    const float* b1 = (const float*)d_in[3];
    const float* W2 = (const float*)d_in[4];
    const float* b2 = (const float*)d_in[5];
    float* out = (float*)d_out;

    const int n = in_sizes[0] / IN_F;     // 100000
    const int E = in_sizes[1] / 2;        // 1600000
    const int* src = ei;
    const int* dst = ei + E;

    const int nb = (n + BKT_NODES - 1) >> BKT_SHIFT;   // 391 buckets (<=512)
    const int nc = nb * NBLK;                          // 200192 cells

    // ---- workspace layout: ~28 MB ----
    int* ip = (int*)d_ws;
    int* cnt       = ip;                 ip += nc;         // 0.8 MB
    int* cellstart = ip;                 ip += nc + 1;     // 0.8 MB
    int* bsum      = ip;                 ip += nb + 1;
    int* rowstart  = ip;                 ip += n + 1;
    unsigned* pairs = (unsigned*)ip;     ip += E;          // 6.4 MB
    int* srcs_srt  = ip;                 ip += E;          // 6.4 MB
    float* dinv = (float*)ip;            ip += n;
    unsigned* xs2  = (unsigned*)ip;      ip += (size_t)n * IN_F / 2;   // 6.4 MB
    unsigned* hs2p = (unsigned*)ip;                                    // 6.4 MB

    count_kernel<<<NBLK, 256, 0, stream>>>(dst, cnt, E, nb);
    bsum_kernel <<<nb, NBLK, 0, stream>>>(cnt, bsum);
    bscan_kernel<<<1, 512, 0, stream>>>(bsum, nb, cellstart, nc, rowstart, n, E);
    cscan_kernel<<<nb, NBLK, 0, stream>>>(cnt, bsum, cellstart);
    append_kernel<<<NBLK, 256, 0, stream>>>(src, dst, cellstart, pairs, E, nb);
    place_kernel<<<nb, 256, 0, stream>>>(cellstart, pairs, x, srcs_srt, rowstart, dinv, xs2, n);

    const int ngrid = (n + 15) / 16;
    fused1_kernel<<<ngrid, 256, 0, stream>>>(rowstart, srcs_srt, xs2, dinv, b1, W1, W2, hs2p, n);
    agg2_kernel<<<ngrid, 256, 0, stream>>>(rowstart, srcs_srt, hs2p, dinv, b2, out, n);
}

// Round 15
// 218.965 us; speedup vs baseline: 1.1420x; 1.0489x over previous
//
#include <hip/hip_runtime.h>

#define IN_F  32
#define HID_F 64
#define OUT_F 32

#define BKT_SHIFT 8            // 256 nodes per bucket
#define BKT_NODES 256
#define NBLK      1024         // partition blocks — count/append edge->block map MUST match

// bf16 helpers (round-to-nearest-even; inputs are finite)
__device__ inline unsigned short f2bf(float f) {
    unsigned u = __float_as_uint(f);
    return (unsigned short)((u + 0x7FFF + ((u >> 16) & 1)) >> 16);
}
// packed-pair unpack: word = (bf16 hi << 16) | bf16 lo ; lo = even feature
__device__ inline float bflo(unsigned w) { return __uint_as_float(w << 16); }
__device__ inline float bfhi(unsigned w) { return __uint_as_float(w & 0xFFFF0000u); }

// ================= phase 1: per-(bucket,block) exact counts =================
__global__ __launch_bounds__(256) void count_kernel(const int* __restrict__ dst,
                                                    int* __restrict__ cnt, int E, int nb)
{
    __shared__ int hist[1024];          // nb <= 1024
    int tid = threadIdx.x;
    for (int i = tid; i < nb; i += 256) hist[i] = 0;
    __syncthreads();
    for (int e = blockIdx.x * 256 + tid; e < E; e += NBLK * 256)
        atomicAdd(&hist[dst[e] >> BKT_SHIFT], 1);
    __syncthreads();
    for (int i = tid; i < nb; i += 256) cnt[i * NBLK + blockIdx.x] = hist[i];
}

// ================= phase 2a: per-bucket totals (one block per bucket) =================
__global__ __launch_bounds__(NBLK) void bsum_kernel(const int* __restrict__ cnt,
                                                    int* __restrict__ bsum)
{
    __shared__ int s[NBLK];
    int tid = threadIdx.x, b = blockIdx.x;
    s[tid] = cnt[b * NBLK + tid];
    __syncthreads();
    for (int off = NBLK / 2; off > 0; off >>= 1) {
        if (tid < off) s[tid] += s[tid + off];
        __syncthreads();
    }
    if (tid == 0) bsum[b] = s[0];
}

// ================= phase 2b: one-block exclusive scan of bucket totals =================
__global__ __launch_bounds__(512) void bscan_kernel(int* __restrict__ bsum, int nb,
                                                    int* __restrict__ cellstart, int nc,
                                                    int* __restrict__ rowstart, int n, int E)
{
    __shared__ int s[512];
    int tid = threadIdx.x;
    int my = (tid < nb) ? bsum[tid] : 0;
    s[tid] = my;
    __syncthreads();
    for (int off = 1; off < 512; off <<= 1) {
        int t = (tid >= off) ? s[tid - off] : 0;
        __syncthreads();
        s[tid] += t;
        __syncthreads();
    }
    if (tid < nb) bsum[tid] = s[tid] - my;      // exclusive bucket start
    if (tid == 0) { cellstart[nc] = E; rowstart[n] = E; }
}

// ================= phase 2c: per-bucket scan of its NBLK cells =================
__global__ __launch_bounds__(NBLK) void cscan_kernel(const int* __restrict__ cnt,
                                                     const int* __restrict__ bsum,
                                                     int* __restrict__ cellstart)
{
    __shared__ int s[NBLK];
    int tid = threadIdx.x, b = blockIdx.x;
    int my = cnt[b * NBLK + tid];
    s[tid] = my;
    __syncthreads();
    for (int off = 1; off < NBLK; off <<= 1) {
        int t = (tid >= off) ? s[tid - off] : 0;
        __syncthreads();
        s[tid] += t;
        __syncthreads();
    }
    cellstart[b * NBLK + tid] = bsum[b] + s[tid] - my;   // exclusive
}

// ================= phase 3: append via block-private LDS cursors =================
__global__ __launch_bounds__(256) void append_kernel(
    const int* __restrict__ src, const int* __restrict__ dst,
    const int* __restrict__ cellstart, unsigned* __restrict__ pairs, int E, int nb)
{
    __shared__ int cur[1024];
    int tid = threadIdx.x;
    for (int i = tid; i < nb; i += 256) cur[i] = cellstart[i * NBLK + blockIdx.x];
    __syncthreads();
    for (int e = blockIdx.x * 256 + tid; e < E; e += NBLK * 256) {
        int d = dst[e];
        int pos = atomicAdd(&cur[d >> BKT_SHIFT], 1);     // LDS atomic
        pairs[pos] = ((unsigned)src[e] << BKT_SHIFT) | (unsigned)(d & (BKT_NODES - 1));
    }
}

// ================= phase 4: place + rowstart + dinv + fused xs build =================
__global__ __launch_bounds__(256) void place_kernel(
    const int* __restrict__ cellstart, const unsigned* __restrict__ pairs,
    const float* __restrict__ x,
    int* __restrict__ srcs, int* __restrict__ rowstart, float* __restrict__ dinv,
    unsigned* __restrict__ xs2, int n)
{
    __shared__ int hist[BKT_NODES];
    __shared__ int ofs[BKT_NODES];
    __shared__ float sdinv[BKT_NODES];
    int b = blockIdx.x, tid = threadIdx.x;
    int beg = cellstart[b * NBLK], end = cellstart[(b + 1) * NBLK];
    hist[tid] = 0;
    __syncthreads();
    for (int e = beg + tid; e < end; e += 256)
        atomicAdd(&hist[pairs[e] & (BKT_NODES - 1)], 1);
    __syncthreads();
    int my = hist[tid];
    ofs[tid] = my;
    __syncthreads();
    for (int off = 1; off < 256; off <<= 1) {
        int t = (tid >= off) ? ofs[tid - off] : 0;
        __syncthreads();
        ofs[tid] += t;
        __syncthreads();
    }
    int excl = ofs[tid] - my;
    int node = b * BKT_NODES + tid;
    float dv = rsqrtf((float)(my + 1));   // +1 self-loop
    sdinv[tid] = dv;
    if (node < n) {
        rowstart[node] = beg + excl;
        dinv[node] = dv;
    }
    __syncthreads();
    ofs[tid] = excl;                    // reuse as LDS cursor
    __syncthreads();
    for (int e = beg + tid; e < end; e += 256) {
        unsigned p = pairs[e];
        int dl = p & (BKT_NODES - 1);
        int pos = beg + atomicAdd(&ofs[dl], 1);
        srcs[pos] = (int)(p >> BKT_SHIFT);
    }
    // fused xs build: xs2[node][q] = packed bf16 pair of dinv[node]*x[node][2q..2q+1]
    const float4* x4 = (const float4*)x;
    uint2* xo = (uint2*)xs2;
    for (int idx = tid; idx < BKT_NODES * 8; idx += 256) {
        int nloc = idx >> 3, g = idx & 7;
        int nd = b * BKT_NODES + nloc;
        if (nd < n) {
            float d = sdinv[nloc];
            float4 v = x4[((size_t)nd << 3) + g];
            unsigned lo = (unsigned)f2bf(v.x * d) | ((unsigned)f2bf(v.y * d) << 16);
            unsigned hi = (unsigned)f2bf(v.z * d) | ((unsigned)f2bf(v.w * d) << 16);
            xo[((size_t)nd << 3) + g] = make_uint2(lo, hi);
        }
    }
}

// ================= fused1: quarter-wave gather -> MLP -> packed bf16 hs2 =================
// (R11 structure — best measured gather format: 16 lanes/node, dword per lane,
//  4 distinct lines per wave-instruction, 8-deep unroll.)
__global__ __launch_bounds__(256) void fused1_kernel(
    const int* __restrict__ rowstart, const int* __restrict__ srcs,
    const unsigned* __restrict__ xs2, const float* __restrict__ dinv,
    const float* __restrict__ b1, const float* __restrict__ W1,
    const float* __restrict__ W2, unsigned* __restrict__ hs2p, int n)
{
    __shared__ float W1s[IN_F * HID_F];    // 8 KB  [k*64+j]
    __shared__ float W2s[HID_F * OUT_F];   // 8 KB  [k*32+j]
    __shared__ float grow[16][IN_F + 1];   // padded
    __shared__ float hrow[16][HID_F + 1];  // padded
    int tid = threadIdx.x;
    for (int t = tid; t < IN_F * HID_F; t += 256) W1s[t] = W1[t];
    for (int t = tid; t < HID_F * OUT_F; t += 256) W2s[t] = W2[t];

    int nl = tid >> 4;
    unsigned q = tid & 15;
    int node = blockIdx.x * 16 + nl;
    bool active = node < n;
    int nodec = active ? node : 0;

    int beg = rowstart[nodec], end = active ? rowstart[nodec + 1] : beg;
    unsigned ws = active ? xs2[((unsigned)nodec << 4) + q] : 0u;   // self-loop
    float a0l = bflo(ws), a0h = bfhi(ws);
    float a1l = 0.f, a1h = 0.f, a2l = 0.f, a2h = 0.f, a3l = 0.f, a3h = 0.f;
    float a4l = 0.f, a4h = 0.f, a5l = 0.f, a5h = 0.f, a6l = 0.f, a6h = 0.f;
    float a7l = 0.f, a7h = 0.f;
    int e = beg;
    for (; e + 8 <= end; e += 8) {
        unsigned o0 = ((unsigned)srcs[e]     << 4) + q, o1 = ((unsigned)srcs[e + 1] << 4) + q;
        unsigned o2 = ((unsigned)srcs[e + 2] << 4) + q, o3 = ((unsigned)srcs[e + 3] << 4) + q;
        unsigned o4 = ((unsigned)srcs[e + 4] << 4) + q, o5 = ((unsigned)srcs[e + 5] << 4) + q;
        unsigned o6 = ((unsigned)srcs[e + 6] << 4) + q, o7 = ((unsigned)srcs[e + 7] << 4) + q;
        unsigned w0 = xs2[o0], w1 = xs2[o1], w2 = xs2[o2], w3 = xs2[o3];
        unsigned w4 = xs2[o4], w5 = xs2[o5], w6 = xs2[o6], w7 = xs2[o7];
        a0l += bflo(w0); a0h += bfhi(w0); a1l += bflo(w1); a1h += bfhi(w1);
        a2l += bflo(w2); a2h += bfhi(w2); a3l += bflo(w3); a3h += bfhi(w3);
        a4l += bflo(w4); a4h += bfhi(w4); a5l += bflo(w5); a5h += bfhi(w5);
        a6l += bflo(w6); a6h += bfhi(w6); a7l += bflo(w7); a7h += bfhi(w7);
    }
    for (; e + 4 <= end; e += 4) {
        unsigned o0 = ((unsigned)srcs[e]     << 4) + q, o1 = ((unsigned)srcs[e + 1] << 4) + q;
        unsigned o2 = ((unsigned)srcs[e + 2] << 4) + q, o3 = ((unsigned)srcs[e + 3] << 4) + q;
        unsigned w0 = xs2[o0], w1 = xs2[o1], w2 = xs2[o2], w3 = xs2[o3];
        a0l += bflo(w0); a0h += bfhi(w0); a1l += bflo(w1); a1h += bfhi(w1);
        a2l += bflo(w2); a2h += bfhi(w2); a3l += bflo(w3); a3h += bfhi(w3);
    }
    for (; e < end; ++e) {
        unsigned w0 = xs2[((unsigned)srcs[e] << 4) + q];
        a0l += bflo(w0); a0h += bfhi(w0);
    }
    float dv = dinv[nodec];
    grow[nl][2 * q]     = dv * (((a0l + a1l) + (a2l + a3l)) + ((a4l + a5l) + (a6l + a7l)));
    grow[nl][2 * q + 1] = dv * (((a0h + a1h) + (a2h + a3h)) + ((a4h + a5h) + (a6h + a7h)));
    __syncthreads();

    // ---- MLP: 16 threads/node. hidden features q, q+16, q+32, q+48 ----
    float h0 = b1[q], h1 = b1[q + 16], h2 = b1[q + 32], h3 = b1[q + 48];
    #pragma unroll
    for (int k = 0; k < IN_F; ++k) {
        float gk = grow[nl][k];
        h0 += gk * W1s[k * HID_F + q];
        h1 += gk * W1s[k * HID_F + q + 16];
        h2 += gk * W1s[k * HID_F + q + 32];
        h3 += gk * W1s[k * HID_F + q + 48];
    }
    hrow[nl][q]      = fmaxf(h0, 0.f);
    hrow[nl][q + 16] = fmaxf(h1, 0.f);
    hrow[nl][q + 32] = fmaxf(h2, 0.f);
    hrow[nl][q + 48] = fmaxf(h3, 0.f);
    __syncthreads();

    // ---- W2 matvec: output features 2q, 2q+1; write packed pair ----
    float p0 = 0.f, p1 = 0.f;
    #pragma unroll
    for (int k = 0; k < HID_F; ++k) {
        float hk = hrow[nl][k];
        p0 += hk * W2s[k * OUT_F + 2 * q];
        p1 += hk * W2s[k * OUT_F + 2 * q + 1];
    }
    if (active) {
        unsigned pack = (unsigned)f2bf(dv * p0) | ((unsigned)f2bf(dv * p1) << 16);
        hs2p[((unsigned)node << 4) + q] = pack;
    }
}

// ================= agg2: quarter-wave gather of packed hs2, finalize =================
__global__ __launch_bounds__(256) void agg2_kernel(
    const int* __restrict__ rowstart, const int* __restrict__ srcs,
    const unsigned* __restrict__ hs2p, const float* __restrict__ dinv,
    const float* __restrict__ b2, float* __restrict__ out, int n)
{
    int t = blockIdx.x * blockDim.x + threadIdx.x;
    int node = t >> 4;
    if (node >= n) return;
    unsigned q = t & 15;
    int beg = rowstart[node], end = rowstart[node + 1];
    unsigned ws = hs2p[((unsigned)node << 4) + q];   // self-loop
    float a0l = bflo(ws), a0h = bfhi(ws);
    float a1l = 0.f, a1h = 0.f, a2l = 0.f, a2h = 0.f, a3l = 0.f, a3h = 0.f;
    float a4l = 0.f, a4h = 0.f, a5l = 0.f, a5h = 0.f, a6l = 0.f, a6h = 0.f;
    float a7l = 0.f, a7h = 0.f;
    int e = beg;
    for (; e + 8 <= end; e += 8) {
        unsigned o0 = ((unsigned)srcs[e]     << 4) + q, o1 = ((unsigned)srcs[e + 1] << 4) + q;
        unsigned o2 = ((unsigned)srcs[e + 2] << 4) + q, o3 = ((unsigned)srcs[e + 3] << 4) + q;
        unsigned o4 = ((unsigned)srcs[e + 4] << 4) + q, o5 = ((unsigned)srcs[e + 5] << 4) + q;
        unsigned o6 = ((unsigned)srcs[e + 6] << 4) + q, o7 = ((unsigned)srcs[e + 7] << 4) + q;
        unsigned w0 = hs2p[o0], w1 = hs2p[o1], w2 = hs2p[o2], w3 = hs2p[o3];
        unsigned w4 = hs2p[o4], w5 = hs2p[o5], w6 = hs2p[o6], w7 = hs2p[o7];
        a0l += bflo(w0); a0h += bfhi(w0); a1l += bflo(w1); a1h += bfhi(w1);
        a2l += bflo(w2); a2h += bfhi(w2); a3l += bflo(w3); a3h += bfhi(w3);
        a4l += bflo(w4); a4h += bfhi(w4); a5l += bflo(w5); a5h += bfhi(w5);
        a6l += bflo(w6); a6h += bfhi(w6); a7l += bflo(w7); a7h += bfhi(w7);
    }
    for (; e + 4 <= end; e += 4) {
        unsigned o0 = ((unsigned)srcs[e]     << 4) + q, o1 = ((unsigned)srcs[e + 1] << 4) + q;
        unsigned o2 = ((unsigned)srcs[e + 2] << 4) + q, o3 = ((unsigned)srcs[e + 3] << 4) + q;
        unsigned w0 = hs2p[o0], w1 = hs2p[o1], w2 = hs2p[o2], w3 = hs2p[o3];
        a0l += bflo(w0); a0h += bfhi(w0); a1l += bflo(w1); a1h += bfhi(w1);
        a2l += bflo(w2); a2h += bfhi(w2); a3l += bflo(w3); a3h += bfhi(w3);
    }
    for (; e < end; ++e) {
        unsigned w0 = hs2p[((unsigned)srcs[e] << 4) + q];
        a0l += bflo(w0); a0h += bfhi(w0);
    }
    float dvv = dinv[node];
    float2 r;
    r.x = dvv * (((a0l + a1l) + (a2l + a3l)) + ((a4l + a5l) + (a6l + a7l))) + b2[2 * q];
    r.y = dvv * (((a0h + a1h) + (a2h + a3h)) + ((a4h + a5h) + (a6h + a7h))) + b2[2 * q + 1];
    ((float2*)out)[((size_t)node << 4) + q] = r;
}

extern "C" void kernel_launch(void* const* d_in, const int* in_sizes, int n_in,
                              void* d_out, int out_size, void* d_ws, size_t ws_size,
                              hipStream_t stream) {
    const float* x  = (const float*)d_in[0];
    const int*   ei = (const int*)  d_in[1];
    const float* W1 = (const float*)d_in[2];
    const float* b1 = (const float*)d_in[3];
    const float* W2 = (const float*)d_in[4];
    const float* b2 = (const float*)d_in[5];
    float* out = (float*)d_out;

    const int n = in_sizes[0] / IN_F;     // 100000
    const int E = in_sizes[1] / 2;        // 1600000
    const int* src = ei;
    const int* dst = ei + E;

    const int nb = (n + BKT_NODES - 1) >> BKT_SHIFT;   // 391 buckets (<=512)
    const int nc = nb * NBLK;                          // 400384 cells

    // ---- workspace layout: ~30 MB ----
    int* ip = (int*)d_ws;
    int* cnt       = ip;                 ip += nc;         // 1.6 MB
    int* cellstart = ip;                 ip += nc + 1;     // 1.6 MB
    int* bsum      = ip;                 ip += nb + 1;
    int* rowstart  = ip;                 ip += n + 1;
    unsigned* pairs = (unsigned*)ip;     ip += E;          // 6.4 MB
    int* srcs_srt  = ip;                 ip += E;          // 6.4 MB
    float* dinv = (float*)ip;            ip += n;
    unsigned* xs2  = (unsigned*)ip;      ip += (size_t)n * IN_F / 2;   // 6.4 MB
    unsigned* hs2p = (unsigned*)ip;                                    // 6.4 MB

    count_kernel<<<NBLK, 256, 0, stream>>>(dst, cnt, E, nb);
    bsum_kernel <<<nb, NBLK, 0, stream>>>(cnt, bsum);
    bscan_kernel<<<1, 512, 0, stream>>>(bsum, nb, cellstart, nc, rowstart, n, E);
    cscan_kernel<<<nb, NBLK, 0, stream>>>(cnt, bsum, cellstart);
    append_kernel<<<NBLK, 256, 0, stream>>>(src, dst, cellstart, pairs, E, nb);
    place_kernel<<<nb, 256, 0, stream>>>(cellstart, pairs, x, srcs_srt, rowstart, dinv, xs2, n);

    fused1_kernel<<<(n + 15) / 16, 256, 0, stream>>>(rowstart, srcs_srt, xs2, dinv, b1, W1, W2, hs2p, n);
    agg2_kernel<<<((size_t)n * 16 + 255) / 256, 256, 0, stream>>>(rowstart, srcs_srt, hs2p, dinv, b2, out, n);
}